// Round 18
// baseline (134.668 us; speedup 1.0000x reference)
//
#include <hip/hip_runtime.h>
#include <hip/hip_fp16.h>
#include <math.h>

// Problem constants
#define BATCH 256
#define CIN 3
#define HW 128
#define OC 16
#define POOLED 63
#define FEAT 63504         // OC*63*63
#define NH 256
#define FANIN 512
#define NO 10

#define PADX 134           // LDS x-stride in halves
#define ROWS 12            // (c,dy) rows
#define NQ 8               // hidden k-splits

typedef _Float16 h4 __attribute__((ext_vector_type(4)));
typedef _Float16 h2v __attribute__((ext_vector_type(2)));
typedef float    f4 __attribute__((ext_vector_type(4)));

// ---------------- Kernel 1: conv3x3+bias+relu+maxpool via MFMA + NT stores -------
// (FROZEN R17: NT store confirmed -5.4us -- featsT lands clean in L3, no
// cross-XCD dirty-handoff storm in hidden.)
__global__ __launch_bounds__(256) void conv_pool_kernel(const float* __restrict__ inp,
                                                        const float* __restrict__ cw,
                                                        const float* __restrict__ cb,
                                                        __half* __restrict__ featsT) {
    __shared__ _Float16 sB[ROWS * 16 * PADX];     // 51,456 B
    const int t    = threadIdx.x;
    const int l    = t & 63;
    const int w    = t >> 6;        // wave 0..3
    const int q    = l >> 4;        // quarter 0..3
    const int bcol = l & 15;        // oc for A/D, batch-col for B

    const int id = blockIdx.x;
    const int u  = id & 7;
    const int v  = id >> 3;          // 0..125
    const int i  = v >> 1;           // pooled row 0..62
    const int g  = 2 * u + (v & 1);  // batch group 0..15
    const int y0 = 2 * i;

#pragma unroll
    for (int bb = 0; bb < 4; ++bb) {
        const int b_l = w * 4 + bb;
#pragma unroll
        for (int rr = 0; rr < 12; ++rr) {
            const int c  = rr >> 2;
            const int dy = rr & 3;
            const float2 vv = *(const float2*)
                &inp[((size_t)(g * 16 + b_l) * CIN + c) * (HW * HW) + (y0 + dy) * HW + 2 * l];
            *(__half2*)&sB[(size_t)((c * 4 + dy) * 16 + b_l) * PADX + 2 * l] =
                __float22half2_rn(vv);
        }
    }
    __syncthreads();

    h4  aF[3][2];
    int bOff[3][2];
    float bias[4];
#pragma unroll
    for (int s = 0; s < 3; ++s) {
        const int rIdx = s * 4 + q;
        const int c    = (rIdx * 11) >> 5;
        const int ky   = rIdx - 3 * c;
        const bool valid = (c < 3);
        float wv[3];
#pragma unroll
        for (int kx = 0; kx < 3; ++kx)
            wv[kx] = valid ? cw[(bcol * CIN + c) * 9 + ky * 3 + kx] : 0.0f;
        aF[s][0][0] = (_Float16)wv[0]; aF[s][0][1] = (_Float16)wv[1];
        aF[s][0][2] = (_Float16)wv[2]; aF[s][0][3] = (_Float16)0.0f;
        aF[s][1][0] = (_Float16)0.0f;  aF[s][1][1] = (_Float16)wv[0];
        aF[s][1][2] = (_Float16)wv[1]; aF[s][1][3] = (_Float16)wv[2];
#pragma unroll
        for (int ys = 0; ys < 2; ++ys) {
            const int row = valid ? (c * 4 + ys + ky) : ys;
            bOff[s][ys] = (row * 16 + bcol) * PADX;
        }
    }
#pragma unroll
    for (int r = 0; r < 4; ++r) bias[r] = cb[4 * q + r];

    const int jend = (16 * w + 16 < 63) ? (16 * w + 16) : 63;
    for (int j = 16 * w; j < jend; ++j) {
        f4 d00 = {0.f,0.f,0.f,0.f}, d01 = d00, d10 = d00, d11 = d00;
#pragma unroll
        for (int s = 0; s < 3; ++s) {
            const _Float16* p0 = &sB[bOff[s][0] + 2 * j];
            const _Float16* p1 = &sB[bOff[s][1] + 2 * j];
            const h2v a0 = *(const h2v*)p0, a1 = *(const h2v*)(p0 + 2);
            const h2v c0 = *(const h2v*)p1, c1 = *(const h2v*)(p1 + 2);
            const h4 bF0 = {a0[0], a0[1], a1[0], a1[1]};
            const h4 bF1 = {c0[0], c0[1], c1[0], c1[1]};
            d00 = __builtin_amdgcn_mfma_f32_16x16x16f16(aF[s][0], bF0, d00, 0, 0, 0);
            d01 = __builtin_amdgcn_mfma_f32_16x16x16f16(aF[s][1], bF0, d01, 0, 0, 0);
            d10 = __builtin_amdgcn_mfma_f32_16x16x16f16(aF[s][0], bF1, d10, 0, 0, 0);
            d11 = __builtin_amdgcn_mfma_f32_16x16x16f16(aF[s][1], bF1, d11, 0, 0, 0);
        }
#pragma unroll
        for (int r = 0; r < 4; ++r) {
            const float mv = fmaxf(fmaxf(d00[r], d01[r]), fmaxf(d10[r], d11[r]));
            const float rv = fmaxf(mv + bias[r], 0.0f);
            const int oc = 4 * q + r;
            const __half hv = __float2half_rn(rv);
            __builtin_nontemporal_store(
                *(const short*)&hv,
                (short*)&featsT[(size_t)(oc * 3969 + i * POOLED + j) * BATCH + g * 16 + bcol]);
        }
    }
}

// ---------------- Kernel 2: sparse hidden layer, concurrency-doubled ------------
// R16/R17 signature: latency-bound gather (VALU 2%, 380GB/s). Little's-law fix,
// both factors x2: (1) grid (256h, 8 k-splits) = 2048 blocks -> 8 blocks/CU ->
// 8 waves/SIMD (was 4); (2) per wave, ALL 8 uint4 rows loaded into a register
// batch BEFORE the FMA block (32 VGPR of destinations -> ~8 outstanding loads
// per thread; R12's VGPR=32 build could hold only ~4).
__global__ __launch_bounds__(256) void hidden_kernel(const __half* __restrict__ featsT,
                                                     const int* __restrict__ hidx,
                                                     const float* __restrict__ hw,
                                                     float* __restrict__ hiddenP) {
    __shared__ int   sidx[64];
    __shared__ float swt[64];
    __shared__ float red[4][256];
    const int h = blockIdx.x;        // 0..255
    const int q = blockIdx.y;        // 0..7
    const int t = threadIdx.x;
    if (t < 64) {
        sidx[t] = hidx[h * FANIN + q * 64 + t];
        swt[t]  = hw[h * FANIN + q * 64 + t];
    }
    __syncthreads();

    const int l   = t & 63;
    const int w   = t >> 6;          // 0..3; wave w owns k in [w*16, w*16+16)
    const int hl  = l & 31;          // b-octet index
    const int sel = l >> 5;          // 0: even k, 1: odd k

    // batch-issue all 8 gathers, then consume
    uint4 vv[8];
    float wt[8];
#pragma unroll
    for (int m = 0; m < 8; ++m) {
        const int kloc = w * 16 + 2 * m + sel;
        vv[m] = *(const uint4*)(featsT + (size_t)sidx[kloc] * BATCH + 8 * hl);
        wt[m] = swt[kloc];
    }
    float acc[8] = {0.f,0.f,0.f,0.f,0.f,0.f,0.f,0.f};
#pragma unroll
    for (int m = 0; m < 8; ++m) {
        const __half2* hp = reinterpret_cast<const __half2*>(&vv[m]);
#pragma unroll
        for (int d2 = 0; d2 < 4; ++d2) {
            const float2 f = __half22float2(hp[d2]);
            acc[2 * d2 + 0] += f.x * wt[m];
            acc[2 * d2 + 1] += f.y * wt[m];
        }
    }
#pragma unroll
    for (int e = 0; e < 8; ++e) acc[e] += __shfl_xor(acc[e], 32);
    if (sel == 0) {
#pragma unroll
        for (int e = 0; e < 8; ++e) red[w][8 * hl + e] = acc[e];
    }
    __syncthreads();

    if (t < 256) {
        const float s = red[0][t] + red[1][t] + red[2][t] + red[3][t];
        hiddenP[((size_t)q * NH + h) * BATCH + t] = s;
    }
}

// ---------------- Kernel 3: 8-partial sum + sigmoid + dense 256->10 -------------
__global__ __launch_bounds__(256) void out_kernel(const float* __restrict__ hiddenP,
                                                  const float* __restrict__ hb,
                                                  const float* __restrict__ ow,
                                                  const float* __restrict__ ob,
                                                  float* __restrict__ out) {
    __shared__ float red[256];
    const int o  = blockIdx.x;
    const int bt = blockIdx.y;
    const int tb = threadIdx.x & 15;
    const int hg = threadIdx.x >> 4;
    const int b  = bt * 16 + tb;
    float acc = 0.f;
#pragma unroll
    for (int k = 0; k < 16; ++k) {
        const int h = hg * 16 + k;
        float s = hb[h];
#pragma unroll
        for (int qq = 0; qq < NQ; ++qq)
            s += hiddenP[((size_t)qq * NH + h) * BATCH + b];
        const float hs = 1.0f / (1.0f + __expf(-s));
        acc += hs * ow[o * NH + h];
    }
    red[threadIdx.x] = acc;
    __syncthreads();
    if (hg == 0) {
        float s = 0.f;
#pragma unroll
        for (int gg = 0; gg < 16; ++gg) s += red[gg * 16 + tb];
        out[b * NO + o] = 1.0f / (1.0f + __expf(-(s + ob[o])));
    }
}

extern "C" void kernel_launch(void* const* d_in, const int* in_sizes, int n_in,
                              void* d_out, int out_size, void* d_ws, size_t ws_size,
                              hipStream_t stream) {
    const float* inputs   = (const float*)d_in[0];
    const float* conv_w   = (const float*)d_in[1];
    const float* conv_b   = (const float*)d_in[2];
    const int*   hidden_i = (const int*)d_in[3];
    const float* hidden_w = (const float*)d_in[4];
    const float* hidden_b = (const float*)d_in[5];
    const float* out_w    = (const float*)d_in[6];
    const float* out_b    = (const float*)d_in[7];
    float* out = (float*)d_out;

    char* ws = (char*)d_ws;
    __half* featsT  = (__half*)ws;                                  // 32,514,048 B
    float*  hiddenP = (float*)(ws + (size_t)FEAT * BATCH * 2);      //  2,097,152 B

    conv_pool_kernel<<<1008, 256, 0, stream>>>(inputs, conv_w, conv_b, featsT);
    hidden_kernel<<<dim3(NH, NQ), 256, 0, stream>>>(featsT, hidden_i, hidden_w, hiddenP);
    out_kernel<<<dim3(NO, 16), 256, 0, stream>>>(hiddenP, hidden_b, out_w, out_b, out);
}